// Round 10
// baseline (3670.528 us; speedup 1.0000x reference)
//
#include <hip/hip_runtime.h>

#define NB 16
#define NN 2048
#define G  64                 // blocks per batch; block owns 32 rows (4 waves x 8 rows)
#define ITERS 100

typedef float v2f __attribute__((ext_vector_type(2)));

static constexpr float INV_N = 1.0f / (float)NN;
static constexpr float NEG_INV_EPS = -10.0f;     // -1/eps, eps = 0.1

__device__ __forceinline__ float fastrcp(float x) { return __builtin_amdgcn_rcpf(x); }

// decode 4 packed fp8-e4m3 bytes -> 4 floats (HW v_cvt_pk_f32_fp8)
__device__ __forceinline__ void dec4(unsigned int u, float& f0, float& f1, float& f2, float& f3) {
    v2f lo = __builtin_amdgcn_cvt_pk_f32_fp8((int)u, false);
    v2f hi = __builtin_amdgcn_cvt_pk_f32_fp8((int)u, true);
    f0 = lo[0]; f1 = lo[1]; f2 = hi[0]; f3 = hi[1];
}

// ------------------------------------------------- build K8 = fp8(K * s_row), INVS = 1/s_row (pow2)
__global__ __launch_bounds__(256) void build_K(const float* __restrict__ x,
                                               const float* __restrict__ y,
                                               unsigned char* __restrict__ K8,
                                               float* __restrict__ INVS) {
    const int n = blockIdx.x, b = blockIdx.y, tid = threadIdx.x;
    const int w = tid >> 6, l = tid & 63;
    const float* xb = x + (size_t)b * 3 * NN;
    const float* yb = y + (size_t)b * 3 * NN;
    const float x0 = xb[n], x1 = xb[NN + n], x2 = xb[2 * NN + n];
    const float xs = x0 * x0 + x1 * x1 + x2 * x2;
    const int m0 = tid * 8;

    const float4 a0 = *(const float4*)(yb + m0);
    const float4 a1 = *(const float4*)(yb + m0 + 4);
    const float4 b0 = *(const float4*)(yb + NN + m0);
    const float4 b1 = *(const float4*)(yb + NN + m0 + 4);
    const float4 c0 = *(const float4*)(yb + 2 * NN + m0);
    const float4 c1 = *(const float4*)(yb + 2 * NN + m0 + 4);
    const float yy0[8] = {a0.x, a0.y, a0.z, a0.w, a1.x, a1.y, a1.z, a1.w};
    const float yy1[8] = {b0.x, b0.y, b0.z, b0.w, b1.x, b1.y, b1.z, b1.w};
    const float yy2[8] = {c0.x, c0.y, c0.z, c0.w, c1.x, c1.y, c1.z, c1.w};

    float k[8];
#pragma unroll
    for (int j = 0; j < 8; ++j) {
        const float ys  = yy0[j] * yy0[j] + yy1[j] * yy1[j] + yy2[j] * yy2[j];
        const float dot = x0 * yy0[j] + x1 * yy1[j] + x2 * yy2[j];
        const float C   = fmaxf(xs + ys - 2.0f * dot, 0.0f);
        k[j] = __expf(NEG_INV_EPS * C);
    }

    // row max -> pow2 scale
    float mx = fmaxf(fmaxf(fmaxf(k[0], k[1]), fmaxf(k[2], k[3])),
                     fmaxf(fmaxf(k[4], k[5]), fmaxf(k[6], k[7])));
#pragma unroll
    for (int off = 32; off > 0; off >>= 1) mx = fmaxf(mx, __shfl_xor(mx, off, 64));
    __shared__ float red[4];
    if (l == 0) red[w] = mx;
    __syncthreads();
    mx = fmaxf(fmaxf(red[0], red[1]), fmaxf(red[2], red[3]));
    mx = fmaxf(mx, 1e-30f);
    const int e = (int)((__float_as_uint(mx) >> 23) & 0xffu) - 127;   // mx in [2^e, 2^{e+1})
    const float sc = __uint_as_float((unsigned)(127 - e) << 23);      // scaled max in [1,2)
    if (tid == 0) INVS[b * NN + n] = __uint_as_float((unsigned)(127 + e) << 23);

    int p0 = __builtin_amdgcn_cvt_pk_fp8_f32(k[0] * sc, k[1] * sc, 0, false);
    p0     = __builtin_amdgcn_cvt_pk_fp8_f32(k[2] * sc, k[3] * sc, p0, true);
    int p1 = __builtin_amdgcn_cvt_pk_fp8_f32(k[4] * sc, k[5] * sc, 0, false);
    p1     = __builtin_amdgcn_cvt_pk_fp8_f32(k[6] * sc, k[7] * sc, p1, true);
    uint2 pk; pk.x = (unsigned)p0; pk.y = (unsigned)p1;
    *(uint2*)(K8 + ((size_t)(b * NN + n)) * NN + m0) = pk;
}

// ------------------------------------------------- reduce: v[m] = inv_n/(sum_g PART[g][m] + 1e-8)
// thread-per-column (coalesced), 128 blocks
__global__ __launch_bounds__(256) void reduce_v(const float* __restrict__ PART,
                                                float* __restrict__ VV) {
    const int t = blockIdx.x * 256 + threadIdx.x;         // t in [0, NB*NN)
    const int b = t >> 11, m = t & (NN - 1);
    const float* p = PART + (size_t)(b * G) * NN + m;
    float s = 0.0f;
#pragma unroll 8
    for (int g = 0; g < G; ++g) s += p[(size_t)g * NN];
    VV[t] = INV_N * fastrcp(s + 1e-8f);
}

// dot of 16 decoded fp8 (one uint4) against vv[16], into d0..d3
#define DOT16(kk, vv) {                                                        \
    float f0_, f1_, f2_, f3_;                                                  \
    dec4(kk.x, f0_, f1_, f2_, f3_);                                            \
    d0 = fmaf(f0_, vv[0], d0);  d1 = fmaf(f1_, vv[1], d1);                     \
    d2 = fmaf(f2_, vv[2], d2);  d3 = fmaf(f3_, vv[3], d3);                     \
    dec4(kk.y, f0_, f1_, f2_, f3_);                                            \
    d0 = fmaf(f0_, vv[4], d0);  d1 = fmaf(f1_, vv[5], d1);                     \
    d2 = fmaf(f2_, vv[6], d2);  d3 = fmaf(f3_, vv[7], d3);                     \
    dec4(kk.z, f0_, f1_, f2_, f3_);                                            \
    d0 = fmaf(f0_, vv[8], d0);  d1 = fmaf(f1_, vv[9], d1);                     \
    d2 = fmaf(f2_, vv[10], d2); d3 = fmaf(f3_, vv[11], d3);                    \
    dec4(kk.w, f0_, f1_, f2_, f3_);                                            \
    d0 = fmaf(f0_, vv[12], d0); d1 = fmaf(f1_, vv[13], d1);                    \
    d2 = fmaf(f2_, vv[14], d2); d3 = fmaf(f3_, vv[15], d3); }

// aa[16] += decode(uint4) * uu
#define ACC16(kk, aa, uu) {                                                    \
    float f0_, f1_, f2_, f3_;                                                  \
    dec4(kk.x, f0_, f1_, f2_, f3_);                                            \
    aa[0] = fmaf(f0_, uu, aa[0]);   aa[1] = fmaf(f1_, uu, aa[1]);              \
    aa[2] = fmaf(f2_, uu, aa[2]);   aa[3] = fmaf(f3_, uu, aa[3]);              \
    dec4(kk.y, f0_, f1_, f2_, f3_);                                            \
    aa[4] = fmaf(f0_, uu, aa[4]);   aa[5] = fmaf(f1_, uu, aa[5]);              \
    aa[6] = fmaf(f2_, uu, aa[6]);   aa[7] = fmaf(f3_, uu, aa[7]);              \
    dec4(kk.z, f0_, f1_, f2_, f3_);                                            \
    aa[8] = fmaf(f0_, uu, aa[8]);   aa[9] = fmaf(f1_, uu, aa[9]);              \
    aa[10] = fmaf(f2_, uu, aa[10]); aa[11] = fmaf(f3_, uu, aa[11]);            \
    dec4(kk.w, f0_, f1_, f2_, f3_);                                            \
    aa[12] = fmaf(f0_, uu, aa[12]); aa[13] = fmaf(f1_, uu, aa[13]);            \
    aa[14] = fmaf(f2_, uu, aa[14]); aa[15] = fmaf(f3_, uu, aa[15]); }

// one pipelined row step. WN = exact outstanding ring-loads allowed after the wait.
// sequence: counted vmcnt -> ds_read row -> dot partials -> lgkm(0) (ds data in VGPR,
// slot free) -> re-issue slot for row R+4 -> butterfly/uw (overlaps loads) -> acc.
#define ROWSTEP(R, WN, INVSR) {                                                           \
    asm volatile("s_waitcnt vmcnt(" #WN ")" ::: "memory");                                \
    __builtin_amdgcn_sched_barrier(0);                                                    \
    const uint4 k0 = *(const uint4*)(ring + ((R) & 3) * 2048 + l * 16);                   \
    const uint4 k1 = *(const uint4*)(ring + ((R) & 3) * 2048 + 1024 + l * 16);            \
    float d = 0.0f;                                                                       \
    if (!first) {                                                                         \
        float d0 = 0, d1 = 0, d2 = 0, d3 = 0;                                             \
        DOT16(k0, v[0]); DOT16(k1, v[1]);                                                 \
        d = (d0 + d1) + (d2 + d3);                                                        \
    }                                                                                     \
    asm volatile("s_waitcnt lgkmcnt(0)" ::: "memory");                                    \
    __builtin_amdgcn_sched_barrier(0);                                                    \
    if ((R) < 4) {                                                                        \
        __builtin_amdgcn_global_load_lds(                                                 \
            (const __attribute__((address_space(1))) void*)(rowg + (size_t)((R) + 4) * NN + l * 16),        \
            (__attribute__((address_space(3))) void*)(ring + ((R) & 3) * 2048), 16, 0, 0);                  \
        __builtin_amdgcn_global_load_lds(                                                 \
            (const __attribute__((address_space(1))) void*)(rowg + (size_t)((R) + 4) * NN + 1024 + l * 16), \
            (__attribute__((address_space(3))) void*)(ring + ((R) & 3) * 2048 + 1024), 16, 0, 0);           \
    }                                                                                     \
    const float invs = (INVSR);                                                           \
    float uw;                                                                             \
    if (first) {                                                                          \
        uw = INV_N * invs;                                                                \
    } else {                                                                              \
        for (int off = 32; off > 0; off >>= 1) d += __shfl_xor(d, off, 64);               \
        uw = INV_N * fastrcp(d * invs + 1e-8f) * invs;                                    \
    }                                                                                     \
    uwsel = (l == (R)) ? uw : uwsel;                                                      \
    ACC16(k0, acc0, uw); ACC16(k1, acc1, uw);                                             \
}

// ------------------------------------------------- fused pass: LDS-ring staged K8 sweep
// wave w owns rows g*32+w*8 .. +7; lane l owns cols {h*1024 + l*16 + j, h<2, j<16}.
__global__ __launch_bounds__(256) void fused_pass(const unsigned char* __restrict__ K8,
                                                  const float* __restrict__ VV,
                                                  const float* __restrict__ INVS,
                                                  float* __restrict__ u_out,
                                                  float* __restrict__ PART,
                                                  int first) {
    const int g = blockIdx.x, b = blockIdx.y, tid = threadIdx.x;
    const int w = tid >> 6, l = tid & 63;

    __shared__ __align__(16) unsigned char smem[32768];   // per-wave 8KB ring, reused as fold buf
    unsigned char* ring = smem + w * 8192;

    float v[2][16];
    if (!first) {
        const float* vb = VV + b * NN + l * 16;
#pragma unroll
        for (int h = 0; h < 2; ++h) {
            const float4 q0 = *(const float4*)(vb + h * 1024);
            const float4 q1 = *(const float4*)(vb + h * 1024 + 4);
            const float4 q2 = *(const float4*)(vb + h * 1024 + 8);
            const float4 q3 = *(const float4*)(vb + h * 1024 + 12);
            v[h][0]  = q0.x; v[h][1]  = q0.y; v[h][2]  = q0.z; v[h][3]  = q0.w;
            v[h][4]  = q1.x; v[h][5]  = q1.y; v[h][6]  = q1.z; v[h][7]  = q1.w;
            v[h][8]  = q2.x; v[h][9]  = q2.y; v[h][10] = q2.z; v[h][11] = q2.w;
            v[h][12] = q3.x; v[h][13] = q3.y; v[h][14] = q3.z; v[h][15] = q3.w;
        }
    }

    float acc0[16], acc1[16];
#pragma unroll
    for (int j = 0; j < 16; ++j) { acc0[j] = 0.0f; acc1[j] = 0.0f; }

    const int row0 = g * 32 + w * 8;
    const unsigned char* rowg = K8 + ((size_t)(b * NN + row0)) * NN;
    const float4 iv0 = *(const float4*)(INVS + b * NN + row0);
    const float4 iv1 = *(const float4*)(INVS + b * NN + row0 + 4);

    // drain ALL prologue vector-memory so counted vmcnt bookkeeping is exact
    asm volatile("s_waitcnt vmcnt(0)" ::: "memory");
    __builtin_amdgcn_sched_barrier(0);

    // prologue: stage rows 0..3 into ring slots 0..3 (8 loads in flight)
#pragma unroll
    for (int rr = 0; rr < 4; ++rr) {
#pragma unroll
        for (int h = 0; h < 2; ++h)
            __builtin_amdgcn_global_load_lds(
                (const __attribute__((address_space(1))) void*)(rowg + (size_t)rr * NN + h * 1024 + l * 16),
                (__attribute__((address_space(3))) void*)(ring + rr * 2048 + h * 1024), 16, 0, 0);
    }

    float uwsel = 0.0f;
    ROWSTEP(0, 6, iv0.x)
    ROWSTEP(1, 6, iv0.y)
    ROWSTEP(2, 6, iv0.z)
    ROWSTEP(3, 6, iv0.w)
    ROWSTEP(4, 6, iv1.x)
    ROWSTEP(5, 4, iv1.y)
    ROWSTEP(6, 2, iv1.z)
    ROWSTEP(7, 0, iv1.w)

    if (l < 8) u_out[b * NN + row0 + l] = uwsel;

    // fold: each wave writes its 2048 column-partials into its own (now-free) ring region
    float* fold = (float*)(smem + w * 8192);
#pragma unroll
    for (int h = 0; h < 2; ++h) {
        float* dst = fold + h * 1024 + l * 16;
        const float* a = h ? acc1 : acc0;
        *(float4*)(dst)      = make_float4(a[0],  a[1],  a[2],  a[3]);
        *(float4*)(dst + 4)  = make_float4(a[4],  a[5],  a[6],  a[7]);
        *(float4*)(dst + 8)  = make_float4(a[8],  a[9],  a[10], a[11]);
        *(float4*)(dst + 12) = make_float4(a[12], a[13], a[14], a[15]);
    }
    __syncthreads();
    const float* f0 = (const float*)(smem);
    const float* f1 = (const float*)(smem + 8192);
    const float* f2 = (const float*)(smem + 16384);
    const float* f3 = (const float*)(smem + 24576);
    float o[8];
#pragma unroll
    for (int j = 0; j < 8; ++j)
        o[j] = (f0[tid * 8 + j] + f1[tid * 8 + j]) + (f2[tid * 8 + j] + f3[tid * 8 + j]);
    float* p = PART + ((size_t)(b * G + g)) * NN + tid * 8;
    *(float4*)(p)     = make_float4(o[0], o[1], o[2], o[3]);
    *(float4*)(p + 4) = make_float4(o[4], o[5], o[6], o[7]);
}

// ------------------------------------------------- final: sum uw[n]*K8[n,m]*C[n,m]*v[m] / B
__global__ __launch_bounds__(256) void final_sum(const unsigned char* __restrict__ K8,
                                                 const float* __restrict__ x,
                                                 const float* __restrict__ y,
                                                 const float* __restrict__ VV,
                                                 const float* __restrict__ u_in,   // holds uw = u*invs
                                                 float* __restrict__ out) {
    const int g = blockIdx.x, b = blockIdx.y, tid = threadIdx.x;
    const int w = tid >> 6, l = tid & 63;
    const float* vb = VV + b * NN;

    float v[4][8];
#pragma unroll
    for (int s = 0; s < 4; ++s) {
        const float4 p0 = *(const float4*)(vb + s * 512 + l * 8);
        const float4 p1 = *(const float4*)(vb + s * 512 + l * 8 + 4);
        v[s][0] = p0.x; v[s][1] = p0.y; v[s][2] = p0.z; v[s][3] = p0.w;
        v[s][4] = p1.x; v[s][5] = p1.y; v[s][6] = p1.z; v[s][7] = p1.w;
    }

    const float* xb = x + (size_t)b * 3 * NN;
    const float* yb = y + (size_t)b * 3 * NN;
    float lacc = 0.0f;

    for (int r = 0; r < 8; ++r) {
        const int n = g * 32 + w * 8 + r;
        const float x0 = xb[n], x1 = xb[NN + n], x2 = xb[2 * NN + n];
        const float xs = x0 * x0 + x1 * x1 + x2 * x2;
        const float uwn = u_in[b * NN + n];
        const unsigned char* Kp = K8 + ((size_t)(b * NN + n)) * NN + l * 8;
        float racc = 0.0f;
#pragma unroll
        for (int s = 0; s < 4; ++s) {
            const int m0 = s * 512 + l * 8;
            const uint2 kv = *(const uint2*)(Kp + s * 512);
            float ky[8];
            dec4(kv.x, ky[0], ky[1], ky[2], ky[3]);
            dec4(kv.y, ky[4], ky[5], ky[6], ky[7]);
            const float4 a0 = *(const float4*)(yb + m0);
            const float4 a1 = *(const float4*)(yb + m0 + 4);
            const float4 b0 = *(const float4*)(yb + NN + m0);
            const float4 b1 = *(const float4*)(yb + NN + m0 + 4);
            const float4 c0 = *(const float4*)(yb + 2 * NN + m0);
            const float4 c1 = *(const float4*)(yb + 2 * NN + m0 + 4);
            const float yy0[8] = {a0.x, a0.y, a0.z, a0.w, a1.x, a1.y, a1.z, a1.w};
            const float yy1[8] = {b0.x, b0.y, b0.z, b0.w, b1.x, b1.y, b1.z, b1.w};
            const float yy2[8] = {c0.x, c0.y, c0.z, c0.w, c1.x, c1.y, c1.z, c1.w};
#pragma unroll
            for (int j = 0; j < 8; ++j) {
                const float ys  = yy0[j] * yy0[j] + yy1[j] * yy1[j] + yy2[j] * yy2[j];
                const float dot = x0 * yy0[j] + x1 * yy1[j] + x2 * yy2[j];
                const float C   = fmaxf(xs + ys - 2.0f * dot, 0.0f);
                racc = fmaf(ky[j] * C, v[s][j], racc);
            }
        }
        lacc = fmaf(uwn, racc, lacc);   // uwn uniform per row: defer lane-reduction
    }
#pragma unroll
    for (int off = 32; off > 0; off >>= 1) lacc += __shfl_xor(lacc, off, 64);
    __shared__ float red[4];
    if (l == 0) red[w] = lacc;
    __syncthreads();
    if (tid == 0) atomicAdd(out, (red[0] + red[1] + red[2] + red[3]) * (1.0f / (float)NB));
}

extern "C" void kernel_launch(void* const* d_in, const int* in_sizes, int n_in,
                              void* d_out, int out_size, void* d_ws, size_t ws_size,
                              hipStream_t stream) {
    const float* x = (const float*)d_in[0];
    const float* y = (const float*)d_in[1];
    float* out = (float*)d_out;
    char* ws = (char*)d_ws;

    unsigned char* K8 = (unsigned char*)ws;                  // 16*2048*2048 = 67,108,864 B
    const size_t KBYTES = (size_t)NB * NN * NN;
    float* PART = (float*)(ws + KBYTES);                     // 16*64*2048*4 = 8 MiB
    const size_t PARTN = (size_t)NB * G * NN;
    float* VV   = PART + PARTN;                              // v vector, 128 KiB
    float* ub   = VV + (size_t)NB * NN;                      // uw vector, 128 KiB
    float* INVS = ub + (size_t)NB * NN;                      // per-row 1/scale, 128 KiB

    hipMemsetAsync(out, 0, sizeof(float), stream);

    build_K<<<dim3(NN, NB), 256, 0, stream>>>(x, y, K8, INVS);

    // iteration 0 half-step: PART <- K^T u0 (u0 = inv_n), phase A skipped
    fused_pass<<<dim3(G, NB), 256, 0, stream>>>(K8, VV, INVS, ub, PART, 1);
    for (int i = 0; i < ITERS; ++i) {
        reduce_v<<<dim3(NB * NN / 256), 256, 0, stream>>>(PART, VV);               // v_k
        fused_pass<<<dim3(G, NB), 256, 0, stream>>>(K8, VV, INVS, ub, PART, 0);    // u_k, PART
    }
    // ub = uw_100, VV = v_100
    final_sum<<<dim3(G, NB), 256, 0, stream>>>(K8, x, y, VV, ub, out);
}

// Round 11
// 2507.390 us; speedup vs baseline: 1.4639x; 1.4639x over previous
//
#include <hip/hip_runtime.h>

#define NB 16
#define NN 2048
#define G  64                 // blocks per batch; block owns 32 rows (4 waves x 8 rows)
#define ITERS 100

typedef float v2f __attribute__((ext_vector_type(2)));

static constexpr float INV_N = 1.0f / (float)NN;
static constexpr float NEG_INV_EPS = -10.0f;     // -1/eps, eps = 0.1

__device__ __forceinline__ float fastrcp(float x) { return __builtin_amdgcn_rcpf(x); }

// decode 4 packed fp8-e4m3 bytes -> 4 floats (HW v_cvt_pk_f32_fp8)
__device__ __forceinline__ void dec4(unsigned int u, float& f0, float& f1, float& f2, float& f3) {
    v2f lo = __builtin_amdgcn_cvt_pk_f32_fp8((int)u, false);
    v2f hi = __builtin_amdgcn_cvt_pk_f32_fp8((int)u, true);
    f0 = lo[0]; f1 = lo[1]; f2 = hi[0]; f3 = hi[1];
}

// ------------------------------------------------- build K8 = fp8(K * s_row), INVS = 1/s_row (pow2)
__global__ __launch_bounds__(256) void build_K(const float* __restrict__ x,
                                               const float* __restrict__ y,
                                               unsigned char* __restrict__ K8,
                                               float* __restrict__ INVS) {
    const int n = blockIdx.x, b = blockIdx.y, tid = threadIdx.x;
    const int w = tid >> 6, l = tid & 63;
    const float* xb = x + (size_t)b * 3 * NN;
    const float* yb = y + (size_t)b * 3 * NN;
    const float x0 = xb[n], x1 = xb[NN + n], x2 = xb[2 * NN + n];
    const float xs = x0 * x0 + x1 * x1 + x2 * x2;
    const int m0 = tid * 8;

    const float4 a0 = *(const float4*)(yb + m0);
    const float4 a1 = *(const float4*)(yb + m0 + 4);
    const float4 b0 = *(const float4*)(yb + NN + m0);
    const float4 b1 = *(const float4*)(yb + NN + m0 + 4);
    const float4 c0 = *(const float4*)(yb + 2 * NN + m0);
    const float4 c1 = *(const float4*)(yb + 2 * NN + m0 + 4);
    const float yy0[8] = {a0.x, a0.y, a0.z, a0.w, a1.x, a1.y, a1.z, a1.w};
    const float yy1[8] = {b0.x, b0.y, b0.z, b0.w, b1.x, b1.y, b1.z, b1.w};
    const float yy2[8] = {c0.x, c0.y, c0.z, c0.w, c1.x, c1.y, c1.z, c1.w};

    float k[8];
#pragma unroll
    for (int j = 0; j < 8; ++j) {
        const float ys  = yy0[j] * yy0[j] + yy1[j] * yy1[j] + yy2[j] * yy2[j];
        const float dot = x0 * yy0[j] + x1 * yy1[j] + x2 * yy2[j];
        const float C   = fmaxf(xs + ys - 2.0f * dot, 0.0f);
        k[j] = __expf(NEG_INV_EPS * C);
    }

    // row max -> pow2 scale
    float mx = fmaxf(fmaxf(fmaxf(k[0], k[1]), fmaxf(k[2], k[3])),
                     fmaxf(fmaxf(k[4], k[5]), fmaxf(k[6], k[7])));
#pragma unroll
    for (int off = 32; off > 0; off >>= 1) mx = fmaxf(mx, __shfl_xor(mx, off, 64));
    __shared__ float red[4];
    if (l == 0) red[w] = mx;
    __syncthreads();
    mx = fmaxf(fmaxf(red[0], red[1]), fmaxf(red[2], red[3]));
    mx = fmaxf(mx, 1e-30f);
    const int e = (int)((__float_as_uint(mx) >> 23) & 0xffu) - 127;   // mx in [2^e, 2^{e+1})
    const float sc = __uint_as_float((unsigned)(127 - e) << 23);      // scaled max in [1,2)
    if (tid == 0) INVS[b * NN + n] = __uint_as_float((unsigned)(127 + e) << 23);

    int p0 = __builtin_amdgcn_cvt_pk_fp8_f32(k[0] * sc, k[1] * sc, 0, false);
    p0     = __builtin_amdgcn_cvt_pk_fp8_f32(k[2] * sc, k[3] * sc, p0, true);
    int p1 = __builtin_amdgcn_cvt_pk_fp8_f32(k[4] * sc, k[5] * sc, 0, false);
    p1     = __builtin_amdgcn_cvt_pk_fp8_f32(k[6] * sc, k[7] * sc, p1, true);
    uint2 pk; pk.x = (unsigned)p0; pk.y = (unsigned)p1;
    *(uint2*)(K8 + ((size_t)(b * NN + n)) * NN + m0) = pk;
}

// ------------------------------------------------- reduce: v[m] = inv_n/(sum_g PART[g][m] + 1e-8)
__global__ __launch_bounds__(256) void reduce_v(const float* __restrict__ PART,
                                                float* __restrict__ VV) {
    const int t = blockIdx.x * 256 + threadIdx.x;         // t in [0, NB*NN)
    const int b = t >> 11, m = t & (NN - 1);
    const float* p = PART + (size_t)(b * G) * NN + m;
    float s = 0.0f;
#pragma unroll 8
    for (int g = 0; g < G; ++g) s += p[(size_t)g * NN];
    VV[t] = INV_N * fastrcp(s + 1e-8f);
}

// dot of 16 decoded fp8 (one uint4) against vv[16], into d0..d3
#define DOT16(kk, vv) {                                                        \
    float f0_, f1_, f2_, f3_;                                                  \
    dec4(kk.x, f0_, f1_, f2_, f3_);                                            \
    d0 = fmaf(f0_, vv[0], d0);  d1 = fmaf(f1_, vv[1], d1);                     \
    d2 = fmaf(f2_, vv[2], d2);  d3 = fmaf(f3_, vv[3], d3);                     \
    dec4(kk.y, f0_, f1_, f2_, f3_);                                            \
    d0 = fmaf(f0_, vv[4], d0);  d1 = fmaf(f1_, vv[5], d1);                     \
    d2 = fmaf(f2_, vv[6], d2);  d3 = fmaf(f3_, vv[7], d3);                     \
    dec4(kk.z, f0_, f1_, f2_, f3_);                                            \
    d0 = fmaf(f0_, vv[8], d0);  d1 = fmaf(f1_, vv[9], d1);                     \
    d2 = fmaf(f2_, vv[10], d2); d3 = fmaf(f3_, vv[11], d3);                    \
    dec4(kk.w, f0_, f1_, f2_, f3_);                                            \
    d0 = fmaf(f0_, vv[12], d0); d1 = fmaf(f1_, vv[13], d1);                    \
    d2 = fmaf(f2_, vv[14], d2); d3 = fmaf(f3_, vv[15], d3); }

// aa[16] += decode(uint4) * uu
#define ACC16(kk, aa, uu) {                                                    \
    float f0_, f1_, f2_, f3_;                                                  \
    dec4(kk.x, f0_, f1_, f2_, f3_);                                            \
    aa[0] = fmaf(f0_, uu, aa[0]);   aa[1] = fmaf(f1_, uu, aa[1]);              \
    aa[2] = fmaf(f2_, uu, aa[2]);   aa[3] = fmaf(f3_, uu, aa[3]);              \
    dec4(kk.y, f0_, f1_, f2_, f3_);                                            \
    aa[4] = fmaf(f0_, uu, aa[4]);   aa[5] = fmaf(f1_, uu, aa[5]);              \
    aa[6] = fmaf(f2_, uu, aa[6]);   aa[7] = fmaf(f3_, uu, aa[7]);              \
    dec4(kk.z, f0_, f1_, f2_, f3_);                                            \
    aa[8] = fmaf(f0_, uu, aa[8]);   aa[9] = fmaf(f1_, uu, aa[9]);              \
    aa[10] = fmaf(f2_, uu, aa[10]); aa[11] = fmaf(f3_, uu, aa[11]);            \
    dec4(kk.w, f0_, f1_, f2_, f3_);                                            \
    aa[12] = fmaf(f0_, uu, aa[12]); aa[13] = fmaf(f1_, uu, aa[13]);            \
    aa[14] = fmaf(f2_, uu, aa[14]); aa[15] = fmaf(f3_, uu, aa[15]); }

// ------------------------------------------------- fused pass (single sweep of K8), round-5 loop,
// uint4 loads: wave w owns rows g*32+w*8 .. +7; lane l owns cols {h*1024 + l*16 + j, h<2, j<16}.
__global__ __launch_bounds__(256) void fused_pass(const unsigned char* __restrict__ K8,
                                                  const float* __restrict__ VV,
                                                  const float* __restrict__ INVS,
                                                  float* __restrict__ u_out,
                                                  float* __restrict__ PART,
                                                  int first) {
    const int g = blockIdx.x, b = blockIdx.y, tid = threadIdx.x;
    const int w = tid >> 6, l = tid & 63;

    float v[2][16];
    if (!first) {
        const float* vb = VV + b * NN + l * 16;
#pragma unroll
        for (int h = 0; h < 2; ++h) {
            const float4 q0 = *(const float4*)(vb + h * 1024);
            const float4 q1 = *(const float4*)(vb + h * 1024 + 4);
            const float4 q2 = *(const float4*)(vb + h * 1024 + 8);
            const float4 q3 = *(const float4*)(vb + h * 1024 + 12);
            v[h][0]  = q0.x; v[h][1]  = q0.y; v[h][2]  = q0.z; v[h][3]  = q0.w;
            v[h][4]  = q1.x; v[h][5]  = q1.y; v[h][6]  = q1.z; v[h][7]  = q1.w;
            v[h][8]  = q2.x; v[h][9]  = q2.y; v[h][10] = q2.z; v[h][11] = q2.w;
            v[h][12] = q3.x; v[h][13] = q3.y; v[h][14] = q3.z; v[h][15] = q3.w;
        }
    }

    float acc0[16], acc1[16];
#pragma unroll
    for (int j = 0; j < 16; ++j) { acc0[j] = 0.0f; acc1[j] = 0.0f; }

    const int row0 = g * 32 + w * 8;
    const unsigned char* Kb = K8 + ((size_t)(b * NN + row0)) * NN + l * 16;
    const float* invp = INVS + b * NN + row0;

#pragma unroll 2
    for (int r = 0; r < 8; ++r) {
        const uint4 k0 = *(const uint4*)(Kb + (size_t)r * NN);
        const uint4 k1 = *(const uint4*)(Kb + (size_t)r * NN + 1024);
        const float invs = invp[r];

        float u;
        if (first) {
            u = INV_N;
        } else {
            float d0 = 0, d1 = 0, d2 = 0, d3 = 0;
            DOT16(k0, v[0]);
            DOT16(k1, v[1]);
            float d = (d0 + d1) + (d2 + d3);
#pragma unroll
            for (int off = 32; off > 0; off >>= 1) d += __shfl_xor(d, off, 64);
            u = INV_N * fastrcp(d * invs + 1e-8f);
        }
        const float uw = u * invs;
        if (l == 0) u_out[b * NN + row0 + r] = uw;

        ACC16(k0, acc0, uw);
        ACC16(k1, acc1, uw);
    }

    // fold 4 waves' column partials via LDS, one store per block
    __shared__ float lds[4][NN];                            // 32 KB
    {
        float* dst = &lds[w][l * 16];
        *(float4*)(dst)          = make_float4(acc0[0],  acc0[1],  acc0[2],  acc0[3]);
        *(float4*)(dst + 4)      = make_float4(acc0[4],  acc0[5],  acc0[6],  acc0[7]);
        *(float4*)(dst + 8)      = make_float4(acc0[8],  acc0[9],  acc0[10], acc0[11]);
        *(float4*)(dst + 12)     = make_float4(acc0[12], acc0[13], acc0[14], acc0[15]);
        *(float4*)(dst + 1024)      = make_float4(acc1[0],  acc1[1],  acc1[2],  acc1[3]);
        *(float4*)(dst + 1024 + 4)  = make_float4(acc1[4],  acc1[5],  acc1[6],  acc1[7]);
        *(float4*)(dst + 1024 + 8)  = make_float4(acc1[8],  acc1[9],  acc1[10], acc1[11]);
        *(float4*)(dst + 1024 + 12) = make_float4(acc1[12], acc1[13], acc1[14], acc1[15]);
    }
    __syncthreads();
    float o[8];
#pragma unroll
    for (int j = 0; j < 8; ++j)
        o[j] = (lds[0][tid * 8 + j] + lds[1][tid * 8 + j]) +
               (lds[2][tid * 8 + j] + lds[3][tid * 8 + j]);
    float* p = PART + ((size_t)(b * G + g)) * NN + tid * 8;
    *(float4*)(p)     = make_float4(o[0], o[1], o[2], o[3]);
    *(float4*)(p + 4) = make_float4(o[4], o[5], o[6], o[7]);
}

// ------------------------------------------------- final: sum uw[n]*K8[n,m]*C[n,m]*v[m] / B
__global__ __launch_bounds__(256) void final_sum(const unsigned char* __restrict__ K8,
                                                 const float* __restrict__ x,
                                                 const float* __restrict__ y,
                                                 const float* __restrict__ VV,
                                                 const float* __restrict__ u_in,   // holds uw = u*invs
                                                 float* __restrict__ out) {
    const int g = blockIdx.x, b = blockIdx.y, tid = threadIdx.x;
    const int w = tid >> 6, l = tid & 63;
    const float* vb = VV + b * NN;

    float v[4][8];
#pragma unroll
    for (int s = 0; s < 4; ++s) {
        const float4 p0 = *(const float4*)(vb + s * 512 + l * 8);
        const float4 p1 = *(const float4*)(vb + s * 512 + l * 8 + 4);
        v[s][0] = p0.x; v[s][1] = p0.y; v[s][2] = p0.z; v[s][3] = p0.w;
        v[s][4] = p1.x; v[s][5] = p1.y; v[s][6] = p1.z; v[s][7] = p1.w;
    }

    const float* xb = x + (size_t)b * 3 * NN;
    const float* yb = y + (size_t)b * 3 * NN;
    float lacc = 0.0f;

    for (int r = 0; r < 8; ++r) {
        const int n = g * 32 + w * 8 + r;
        const float x0 = xb[n], x1 = xb[NN + n], x2 = xb[2 * NN + n];
        const float xs = x0 * x0 + x1 * x1 + x2 * x2;
        const float uwn = u_in[b * NN + n];
        const unsigned char* Kp = K8 + ((size_t)(b * NN + n)) * NN + l * 8;
        float racc = 0.0f;
#pragma unroll
        for (int s = 0; s < 4; ++s) {
            const int m0 = s * 512 + l * 8;
            const uint2 kv = *(const uint2*)(Kp + s * 512);
            float ky[8];
            dec4(kv.x, ky[0], ky[1], ky[2], ky[3]);
            dec4(kv.y, ky[4], ky[5], ky[6], ky[7]);
            const float4 a0 = *(const float4*)(yb + m0);
            const float4 a1 = *(const float4*)(yb + m0 + 4);
            const float4 b0 = *(const float4*)(yb + NN + m0);
            const float4 b1 = *(const float4*)(yb + NN + m0 + 4);
            const float4 c0 = *(const float4*)(yb + 2 * NN + m0);
            const float4 c1 = *(const float4*)(yb + 2 * NN + m0 + 4);
            const float yy0[8] = {a0.x, a0.y, a0.z, a0.w, a1.x, a1.y, a1.z, a1.w};
            const float yy1[8] = {b0.x, b0.y, b0.z, b0.w, b1.x, b1.y, b1.z, b1.w};
            const float yy2[8] = {c0.x, c0.y, c0.z, c0.w, c1.x, c1.y, c1.z, c1.w};
#pragma unroll
            for (int j = 0; j < 8; ++j) {
                const float ys  = yy0[j] * yy0[j] + yy1[j] * yy1[j] + yy2[j] * yy2[j];
                const float dot = x0 * yy0[j] + x1 * yy1[j] + x2 * yy2[j];
                const float C   = fmaxf(xs + ys - 2.0f * dot, 0.0f);
                racc = fmaf(ky[j] * C, v[s][j], racc);
            }
        }
        lacc = fmaf(uwn, racc, lacc);   // uwn uniform per row: defer lane-reduction
    }
#pragma unroll
    for (int off = 32; off > 0; off >>= 1) lacc += __shfl_xor(lacc, off, 64);
    __shared__ float red[4];
    if (l == 0) red[w] = lacc;
    __syncthreads();
    if (tid == 0) atomicAdd(out, (red[0] + red[1] + red[2] + red[3]) * (1.0f / (float)NB));
}

extern "C" void kernel_launch(void* const* d_in, const int* in_sizes, int n_in,
                              void* d_out, int out_size, void* d_ws, size_t ws_size,
                              hipStream_t stream) {
    const float* x = (const float*)d_in[0];
    const float* y = (const float*)d_in[1];
    float* out = (float*)d_out;
    char* ws = (char*)d_ws;

    unsigned char* K8 = (unsigned char*)ws;                  // 16*2048*2048 = 67,108,864 B
    const size_t KBYTES = (size_t)NB * NN * NN;
    float* PART = (float*)(ws + KBYTES);                     // 16*64*2048*4 = 8 MiB
    const size_t PARTN = (size_t)NB * G * NN;
    float* VV   = PART + PARTN;                              // v vector, 128 KiB
    float* ub   = VV + (size_t)NB * NN;                      // uw vector, 128 KiB
    float* INVS = ub + (size_t)NB * NN;                      // per-row 1/scale, 128 KiB

    hipMemsetAsync(out, 0, sizeof(float), stream);

    build_K<<<dim3(NN, NB), 256, 0, stream>>>(x, y, K8, INVS);

    // iteration 0 half-step: PART <- K^T u0 (u0 = inv_n), phase A skipped
    fused_pass<<<dim3(G, NB), 256, 0, stream>>>(K8, VV, INVS, ub, PART, 1);
    for (int i = 0; i < ITERS; ++i) {
        reduce_v<<<dim3(NB * NN / 256), 256, 0, stream>>>(PART, VV);               // v_k
        fused_pass<<<dim3(G, NB), 256, 0, stream>>>(K8, VV, INVS, ub, PART, 0);    // u_k, PART
    }
    // ub = uw_100, VV = v_100
    final_sum<<<dim3(G, NB), 256, 0, stream>>>(K8, x, y, VV, ub, out);
}